// Round 3
// baseline (920.229 us; speedup 1.0000x reference)
//
#include <hip/hip_runtime.h>
#include <stdint.h>

#define NN 50000
#define EE 800000
#define IN_DIM 128
#define OUT_DIM 32
#define HEADS 8
#define FF 256
#define SH 128

__device__ __forceinline__ float b2f(unsigned short u) {
    union { unsigned int i; float f; } v; v.i = ((unsigned int)u) << 16; return v.f;
}
__device__ __forceinline__ unsigned short f2b(float f) {
    union { float f; unsigned int i; } v; v.f = f;
    unsigned int i = v.i;
    unsigned int r = (i + 0x7FFFu + ((i >> 16) & 1u)) >> 16;
    return (unsigned short)r;
}

// feat[n, f] = sum_k h[n,k] * W[k,f]   (fp32 in, fp32 acc, bf16 out)
__global__ __launch_bounds__(256) void gemm_feat_kernel(
    const float* __restrict__ h,   // [N,128]
    const float* __restrict__ W,   // [128,256]
    unsigned short* __restrict__ feat)      // [N,256] bf16
{
    __shared__ float hs[32][IN_DIM];  // 16KB
    const int t = threadIdx.x;
    const int n0 = blockIdx.x * 32;
    // stage 32x128 fp32 rows of h into LDS
    #pragma unroll
    for (int it = 0; it < 4; ++it) {
        int v = t + it * 256;          // 1024 x float4 total
        int row = v >> 5;              // 32 float4 per row
        int c4 = (v & 31) * 4;
        int n = n0 + row;
        float4 d = make_float4(0.f, 0.f, 0.f, 0.f);
        if (n < NN) d = *(const float4*)(h + (size_t)n * IN_DIM + c4);
        *(float4*)&hs[row][c4] = d;
    }
    __syncthreads();
    float acc[32];
    #pragma unroll
    for (int i = 0; i < 32; ++i) acc[i] = 0.f;
    for (int kb = 0; kb < IN_DIM; kb += 8) {
        float wv[8];
        #pragma unroll
        for (int u = 0; u < 8; ++u) wv[u] = W[(size_t)(kb + u) * FF + t];
        #pragma unroll
        for (int i = 0; i < 32; ++i) {
            float4 h0 = *(const float4*)&hs[i][kb];
            float4 h1 = *(const float4*)&hs[i][kb + 4];
            acc[i] += h0.x * wv[0] + h0.y * wv[1] + h0.z * wv[2] + h0.w * wv[3]
                    + h1.x * wv[4] + h1.y * wv[5] + h1.z * wv[6] + h1.w * wv[7];
        }
    }
    #pragma unroll
    for (int i = 0; i < 32; ++i) {
        int n = n0 + i;
        if (n < NN) feat[(size_t)n * FF + t] = f2b(acc[i]);
    }
}

// el[n,h] = sum_d feat[n,h,d]*al[h,d]; er likewise  (al/ar fp32, feat bf16)
__global__ __launch_bounds__(256) void elr_kernel(
    const unsigned short* __restrict__ feat,
    const float* __restrict__ al,
    const float* __restrict__ ar,
    float* __restrict__ el, float* __restrict__ er)
{
    int n = blockIdx.x;
    int f = threadIdx.x;
    float v = b2f(feat[(size_t)n * FF + f]);
    float pl = v * al[f];
    float pr = v * ar[f];
    #pragma unroll
    for (int o = 16; o > 0; o >>= 1) {
        pl += __shfl_xor(pl, o, 32);
        pr += __shfl_xor(pr, o, 32);
    }
    if ((f & 31) == 0) {
        el[n * HEADS + (f >> 5)] = pl;
        er[n * HEADS + (f >> 5)] = pr;
    }
}

__global__ void count_kernel(const int* __restrict__ dst, int* __restrict__ counts) {
    int e = blockIdx.x * blockDim.x + threadIdx.x;
    if (e < EE) atomicAdd(&counts[dst[e]], 1);
}

__global__ __launch_bounds__(256) void scan1_kernel(
    const int* __restrict__ counts, int* __restrict__ offs, int* __restrict__ bsums)
{
    __shared__ int sm[256];
    int t = threadIdx.x, i = blockIdx.x * 256 + t;
    int v = (i < NN) ? counts[i] : 0;
    sm[t] = v; __syncthreads();
    for (int d = 1; d < 256; d <<= 1) {
        int x = (t >= d) ? sm[t - d] : 0;
        __syncthreads();
        sm[t] += x;
        __syncthreads();
    }
    if (i < NN) offs[i] = sm[t] - v;          // local exclusive
    if (t == 255) bsums[blockIdx.x] = sm[255]; // block total
}

__global__ __launch_bounds__(256) void scan2_kernel(
    int* __restrict__ bsums, int* __restrict__ offs, int nblk)
{
    __shared__ int sm[256];
    int t = threadIdx.x;
    int v = (t < nblk) ? bsums[t] : 0;
    sm[t] = v; __syncthreads();
    for (int d = 1; d < 256; d <<= 1) {
        int x = (t >= d) ? sm[t - d] : 0;
        __syncthreads();
        sm[t] += x;
        __syncthreads();
    }
    if (t < nblk) bsums[t] = sm[t] - v;
    if (t == 0) offs[NN] = EE;
}

__global__ __launch_bounds__(256) void scan3_kernel(
    int* __restrict__ offs, const int* __restrict__ bsums, int* __restrict__ cursor)
{
    int t = threadIdx.x, i = blockIdx.x * 256 + t;
    if (i < NN) {
        int v = offs[i] + bsums[blockIdx.x];
        offs[i] = v;
        cursor[i] = v;
    }
}

// scatter edges into CSR slots; also compute leaky-relu edge logits, permuted
__global__ void fill_kernel(const int* __restrict__ src, const int* __restrict__ dst,
                            const float* __restrict__ el, const float* __restrict__ er,
                            int* __restrict__ cursor, int* __restrict__ src_perm,
                            float* __restrict__ e_perm)
{
    int e = blockIdx.x * blockDim.x + threadIdx.x;
    if (e >= EE) return;
    int s = src[e], d = dst[e];
    int slot = atomicAdd(&cursor[d], 1);
    src_perm[slot] = s;
    float4 l0 = *(const float4*)(el + s * HEADS);
    float4 l1 = *(const float4*)(el + s * HEADS + 4);
    float4 r0 = *(const float4*)(er + d * HEADS);
    float4 r1 = *(const float4*)(er + d * HEADS + 4);
    float x[8];
    x[0] = l0.x + r0.x; x[1] = l0.y + r0.y; x[2] = l0.z + r0.z; x[3] = l0.w + r0.w;
    x[4] = l1.x + r1.x; x[5] = l1.y + r1.y; x[6] = l1.z + r1.z; x[7] = l1.w + r1.w;
    float4 o0, o1;
    o0.x = (x[0] > 0.f) ? x[0] : 0.2f * x[0];
    o0.y = (x[1] > 0.f) ? x[1] : 0.2f * x[1];
    o0.z = (x[2] > 0.f) ? x[2] : 0.2f * x[2];
    o0.w = (x[3] > 0.f) ? x[3] : 0.2f * x[3];
    o1.x = (x[4] > 0.f) ? x[4] : 0.2f * x[4];
    o1.y = (x[5] > 0.f) ? x[5] : 0.2f * x[5];
    o1.z = (x[6] > 0.f) ? x[6] : 0.2f * x[6];
    o1.w = (x[7] > 0.f) ? x[7] : 0.2f * x[7];
    *(float4*)(e_perm + (size_t)slot * HEADS) = o0;
    *(float4*)(e_perm + (size_t)slot * HEADS + 4) = o1;
}

// one wave per dst node: edge softmax + weighted feat aggregation + bias + ELU
__global__ __launch_bounds__(256) void pull_kernel(
    const int* __restrict__ offs, const int* __restrict__ src_perm,
    const float* __restrict__ e_perm, const unsigned short* __restrict__ feat,
    const float* __restrict__ bias, float* __restrict__ z)
{
    int wave = threadIdx.x >> 6;
    int lane = threadIdx.x & 63;
    int n = blockIdx.x * 4 + wave;
    if (n >= NN) return;
    int head = lane >> 3;     // 8 lanes per head
    int f0 = lane * 4;        // 4 contiguous features per lane, all same head
    int j0 = offs[n], j1 = offs[n + 1];
    float m = -1e30f;
    for (int j = j0; j < j1; ++j) m = fmaxf(m, e_perm[j * HEADS + head]);
    float den = 0.f;
    float a0 = 0.f, a1 = 0.f, a2 = 0.f, a3 = 0.f;
    for (int j = j0; j < j1; ++j) {
        float ex = __expf(e_perm[j * HEADS + head] - m);
        den += ex;
        int s = src_perm[j];
        ushort4 fv = *(const ushort4*)(feat + (size_t)s * FF + f0);
        a0 += b2f(fv.x) * ex;
        a1 += b2f(fv.y) * ex;
        a2 += b2f(fv.z) * ex;
        a3 += b2f(fv.w) * ex;
    }
    if (den <= 0.f) den = 1.f;
    float inv = 1.f / den;
    float o0 = a0 * inv + bias[f0 + 0];
    float o1 = a1 * inv + bias[f0 + 1];
    float o2 = a2 * inv + bias[f0 + 2];
    float o3 = a3 * inv + bias[f0 + 3];
    float4 r;
    r.x = (o0 > 0.f) ? o0 : (__expf(o0) - 1.f);
    r.y = (o1 > 0.f) ? o1 : (__expf(o1) - 1.f);
    r.z = (o2 > 0.f) ? o2 : (__expf(o2) - 1.f);
    r.w = (o3 > 0.f) ? o3 : (__expf(o3) - 1.f);
    *(float4*)(z + (size_t)n * FF + f0) = r;
}

// qsum[idx] += sum_n tanh(z[n]@Wsem + bsem) @ wsem   (32 nodes per block)
__global__ __launch_bounds__(256) void sem_kernel(
    const float* __restrict__ z,      // [N,256] fp32
    const float* __restrict__ Wsem,   // [256,128]
    const float* __restrict__ bsem,   // [128]
    const float* __restrict__ wsem,   // [128]
    float* __restrict__ qsum, int idx)
{
    __shared__ float zs[32][FF];   // 32KB; reused as reduction buffer later
    __shared__ float qn[32];
    const int t = threadIdx.x;
    const int n0 = blockIdx.x * 32;
    #pragma unroll
    for (int it = 0; it < 8; ++it) {
        int v = t + it * 256;      // 2048 x float4 total
        int row = v >> 6;          // 64 float4 per row
        int c4 = (v & 63) * 4;
        int n = n0 + row;
        float4 d = make_float4(0.f, 0.f, 0.f, 0.f);
        if (n < NN) d = *(const float4*)(z + (size_t)n * FF + c4);
        *(float4*)&zs[row][c4] = d;
    }
    __syncthreads();
    const int j = t & 127;
    const int half = t >> 7;
    float val[16];
    #pragma unroll
    for (int i = 0; i < 16; ++i) val[i] = 0.f;
    for (int f = 0; f < FF; f += 4) {
        float w0 = Wsem[(size_t)(f + 0) * SH + j];
        float w1 = Wsem[(size_t)(f + 1) * SH + j];
        float w2 = Wsem[(size_t)(f + 2) * SH + j];
        float w3 = Wsem[(size_t)(f + 3) * SH + j];
        #pragma unroll
        for (int i = 0; i < 16; ++i) {
            float4 zv = *(const float4*)&zs[half * 16 + i][f];
            val[i] += zv.x * w0 + zv.y * w1 + zv.z * w2 + zv.w * w3;
        }
    }
    float bj = bsem[j];
    float wj = wsem[j];
    __syncthreads();
    float* red = &zs[0][0];        // [32][128]
    #pragma unroll
    for (int i = 0; i < 16; ++i)
        red[(half * 16 + i) * SH + j] = tanhf(val[i] + bj) * wj;
    __syncthreads();
    int node = t >> 3, k = t & 7;
    float s = 0.f;
    #pragma unroll
    for (int u = 0; u < 16; ++u) s += red[node * SH + k * 16 + u];
    #pragma unroll
    for (int o = 4; o > 0; o >>= 1) s += __shfl_down(s, o, 8);
    if (k == 0) qn[node] = s;
    __syncthreads();
    if (t == 0) {
        int nv = NN - n0; if (nv > 32) nv = 32;
        float tot = 0.f;
        for (int i = 0; i < nv; ++i) tot += qn[i];
        atomicAdd(&qsum[idx], tot);
    }
}

// out = beta0*z_a + beta1*z_b   (z_b already in out; beta from qsum inline)
__global__ void combine_kernel(const float* __restrict__ za,
                               float* __restrict__ out,
                               const float* __restrict__ qsum)
{
    size_t i = (size_t)blockIdx.x * blockDim.x + threadIdx.x;
    size_t base = i * 4;
    if (base >= (size_t)NN * FF) return;
    float qa = qsum[0] * (1.f / NN), qb = qsum[1] * (1.f / NN);
    float mx = fmaxf(qa, qb);
    float ea = __expf(qa - mx), eb = __expf(qb - mx);
    float inv = 1.f / (ea + eb);
    float b0 = ea * inv, b1 = eb * inv;
    float4 va = *(const float4*)(za + base);
    float4 vb = *(const float4*)(out + base);
    float4 r;
    r.x = b0 * va.x + b1 * vb.x;
    r.y = b0 * va.y + b1 * vb.y;
    r.z = b0 * va.z + b1 * vb.z;
    r.w = b0 * va.w + b1 * vb.w;
    *(float4*)(out + base) = r;
}

extern "C" void kernel_launch(void* const* d_in, const int* in_sizes, int n_in,
                              void* d_out, int out_size, void* d_ws, size_t ws_size,
                              hipStream_t stream)
{
    const float* h      = (const float*)d_in[0];
    const int* src_a    = (const int*)d_in[1];
    const int* dst_a    = (const int*)d_in[2];
    const int* src_b    = (const int*)d_in[3];
    const int* dst_b    = (const int*)d_in[4];
    const float* W_a    = (const float*)d_in[5];
    const float* al_a   = (const float*)d_in[6];
    const float* ar_a   = (const float*)d_in[7];
    const float* bias_a = (const float*)d_in[8];
    const float* W_b    = (const float*)d_in[9];
    const float* al_b   = (const float*)d_in[10];
    const float* ar_b   = (const float*)d_in[11];
    const float* bias_b = (const float*)d_in[12];
    const float* Wsem   = (const float*)d_in[13];
    const float* bsem   = (const float*)d_in[14];
    const float* wsem   = (const float*)d_in[15];
    float* out = (float*)d_out;

    char* ws = (char*)d_ws;
    size_t o = 0;
    auto alloc = [&](size_t bytes) -> char* {
        char* p = ws + o;
        o += (bytes + 255) & ~(size_t)255;
        return p;
    };
    unsigned short* feat = (unsigned short*)alloc((size_t)NN * FF * 2); // bf16
    float* z_a     = (float*)alloc((size_t)NN * FF * 4);
    float* e_perm  = (float*)alloc((size_t)EE * HEADS * 4);
    float* el      = (float*)alloc((size_t)NN * HEADS * 4);
    float* er      = (float*)alloc((size_t)NN * HEADS * 4);
    int* counts    = (int*)alloc((size_t)NN * 4);
    int* offs      = (int*)alloc((size_t)(NN + 1) * 4);
    int* cursor    = (int*)alloc((size_t)NN * 4);
    int* bsums     = (int*)alloc(256 * 4);
    int* src_perm  = (int*)alloc((size_t)EE * 4);
    float* qsum    = (float*)alloc(8);

    hipMemsetAsync(qsum, 0, 8, stream);

    const int nblk_scan = (NN + 255) / 256;

    for (int mp = 0; mp < 2; ++mp) {
        const int* src = mp ? src_b : src_a;
        const int* dst = mp ? dst_b : dst_a;
        const float* W    = mp ? W_b : W_a;
        const float* al   = mp ? al_b : al_a;
        const float* ar   = mp ? ar_b : ar_a;
        const float* bias = mp ? bias_b : bias_a;
        float* z = mp ? out : z_a;

        gemm_feat_kernel<<<(NN + 31) / 32, 256, 0, stream>>>(h, W, feat);
        elr_kernel<<<NN, 256, 0, stream>>>(feat, al, ar, el, er);
        hipMemsetAsync(counts, 0, (size_t)NN * 4, stream);
        count_kernel<<<(EE + 255) / 256, 256, 0, stream>>>(dst, counts);
        scan1_kernel<<<nblk_scan, 256, 0, stream>>>(counts, offs, bsums);
        scan2_kernel<<<1, 256, 0, stream>>>(bsums, offs, nblk_scan);
        scan3_kernel<<<nblk_scan, 256, 0, stream>>>(offs, bsums, cursor);
        fill_kernel<<<(EE + 255) / 256, 256, 0, stream>>>(src, dst, el, er, cursor, src_perm, e_perm);
        pull_kernel<<<(NN + 3) / 4, 256, 0, stream>>>(offs, src_perm, e_perm, feat, bias, z);
        sem_kernel<<<(NN + 31) / 32, 256, 0, stream>>>(z, Wsem, bsem, wsem, qsum, mp);
    }
    combine_kernel<<<(int)(((size_t)NN * FF / 4 + 255) / 256), 256, 0, stream>>>(z_a, out, qsum);
}

// Round 4
// 811.476 us; speedup vs baseline: 1.1340x; 1.1340x over previous
//
#include <hip/hip_runtime.h>
#include <stdint.h>

#define NN 50000
#define EE 800000
#define IN_DIM 128
#define OUT_DIM 32
#define HEADS 8
#define FF 256
#define SH 128

__device__ __forceinline__ float b2f(unsigned short u) {
    union { unsigned int i; float f; } v; v.i = ((unsigned int)u) << 16; return v.f;
}
__device__ __forceinline__ unsigned short f2b(float f) {
    union { float f; unsigned int i; } v; v.f = f;
    unsigned int i = v.i;
    unsigned int r = (i + 0x7FFFu + ((i >> 16) & 1u)) >> 16;
    return (unsigned short)r;
}

// feat[n, f] = sum_k h[n,k] * W[k,f]   (fp32 in, fp32 acc, bf16 out)
__global__ __launch_bounds__(256) void gemm_feat_kernel(
    const float* __restrict__ h,   // [N,128]
    const float* __restrict__ W,   // [128,256]
    unsigned short* __restrict__ feat)      // [N,256] bf16
{
    __shared__ float hs[32][IN_DIM];  // 16KB
    const int t = threadIdx.x;
    const int n0 = blockIdx.x * 32;
    #pragma unroll
    for (int it = 0; it < 4; ++it) {
        int v = t + it * 256;          // 1024 x float4 total
        int row = v >> 5;              // 32 float4 per row
        int c4 = (v & 31) * 4;
        int n = n0 + row;
        float4 d = make_float4(0.f, 0.f, 0.f, 0.f);
        if (n < NN) d = *(const float4*)(h + (size_t)n * IN_DIM + c4);
        *(float4*)&hs[row][c4] = d;
    }
    __syncthreads();
    float acc[32];
    #pragma unroll
    for (int i = 0; i < 32; ++i) acc[i] = 0.f;
    for (int kb = 0; kb < IN_DIM; kb += 8) {
        float wv[8];
        #pragma unroll
        for (int u = 0; u < 8; ++u) wv[u] = W[(size_t)(kb + u) * FF + t];
        #pragma unroll
        for (int i = 0; i < 32; ++i) {
            float4 h0 = *(const float4*)&hs[i][kb];
            float4 h1 = *(const float4*)&hs[i][kb + 4];
            acc[i] += h0.x * wv[0] + h0.y * wv[1] + h0.z * wv[2] + h0.w * wv[3]
                    + h1.x * wv[4] + h1.y * wv[5] + h1.z * wv[6] + h1.w * wv[7];
        }
    }
    #pragma unroll
    for (int i = 0; i < 32; ++i) {
        int n = n0 + i;
        if (n < NN) feat[(size_t)n * FF + t] = f2b(acc[i]);
    }
}

// el[n,h] = sum_d feat[n,h,d]*al[h,d]; er likewise  (al/ar fp32, feat bf16)
__global__ __launch_bounds__(256) void elr_kernel(
    const unsigned short* __restrict__ feat,
    const float* __restrict__ al,
    const float* __restrict__ ar,
    float* __restrict__ el, float* __restrict__ er)
{
    int n = blockIdx.x;
    int f = threadIdx.x;
    float v = b2f(feat[(size_t)n * FF + f]);
    float pl = v * al[f];
    float pr = v * ar[f];
    #pragma unroll
    for (int o = 16; o > 0; o >>= 1) {
        pl += __shfl_xor(pl, o, 32);
        pr += __shfl_xor(pr, o, 32);
    }
    if ((f & 31) == 0) {
        el[n * HEADS + (f >> 5)] = pl;
        er[n * HEADS + (f >> 5)] = pr;
    }
}

__global__ void count_kernel(const int* __restrict__ dst, int* __restrict__ counts) {
    int e = blockIdx.x * blockDim.x + threadIdx.x;
    if (e < EE) atomicAdd(&counts[dst[e]], 1);
}

__global__ __launch_bounds__(256) void scan1_kernel(
    const int* __restrict__ counts, int* __restrict__ offs, int* __restrict__ bsums)
{
    __shared__ int sm[256];
    int t = threadIdx.x, i = blockIdx.x * 256 + t;
    int v = (i < NN) ? counts[i] : 0;
    sm[t] = v; __syncthreads();
    for (int d = 1; d < 256; d <<= 1) {
        int x = (t >= d) ? sm[t - d] : 0;
        __syncthreads();
        sm[t] += x;
        __syncthreads();
    }
    if (i < NN) offs[i] = sm[t] - v;          // local exclusive
    if (t == 255) bsums[blockIdx.x] = sm[255]; // block total
}

__global__ __launch_bounds__(256) void scan2_kernel(
    int* __restrict__ bsums, int* __restrict__ offs, int nblk)
{
    __shared__ int sm[256];
    int t = threadIdx.x;
    int v = (t < nblk) ? bsums[t] : 0;
    sm[t] = v; __syncthreads();
    for (int d = 1; d < 256; d <<= 1) {
        int x = (t >= d) ? sm[t - d] : 0;
        __syncthreads();
        sm[t] += x;
        __syncthreads();
    }
    if (t < nblk) bsums[t] = sm[t] - v;
    if (t == 0) offs[NN] = EE;
}

__global__ __launch_bounds__(256) void scan3_kernel(
    int* __restrict__ offs, const int* __restrict__ bsums, int* __restrict__ cursor)
{
    int t = threadIdx.x, i = blockIdx.x * 256 + t;
    if (i < NN) {
        int v = offs[i] + bsums[blockIdx.x];
        offs[i] = v;
        cursor[i] = v;
    }
}

// scatter src index into CSR slots (4 B per edge; logits computed in pull)
__global__ void fill_kernel(const int* __restrict__ src, const int* __restrict__ dst,
                            int* __restrict__ cursor, int* __restrict__ src_perm)
{
    int e = blockIdx.x * blockDim.x + threadIdx.x;
    if (e >= EE) return;
    int slot = atomicAdd(&cursor[dst[e]], 1);
    src_perm[slot] = src[e];
}

// one wave per dst node, single pass: softmax (no max-shift; logits are small)
// + weighted feat aggregation + bias + ELU
__global__ __launch_bounds__(256) void pull_kernel(
    const int* __restrict__ offs, const int* __restrict__ src_perm,
    const float* __restrict__ el, const float* __restrict__ er,
    const unsigned short* __restrict__ feat,
    const float* __restrict__ bias, float* __restrict__ z)
{
    int wave = threadIdx.x >> 6;
    int lane = threadIdx.x & 63;
    int n = blockIdx.x * 4 + wave;
    if (n >= NN) return;
    int head = lane >> 3;     // 8 lanes per head
    int f0 = lane * 4;        // 4 contiguous features per lane, all same head
    int j0 = offs[n], j1 = offs[n + 1];
    float ern = er[n * HEADS + head];
    float den = 0.f;
    float a0 = 0.f, a1 = 0.f, a2 = 0.f, a3 = 0.f;

#define EDGE_STEP(S) {                                              \
        float x = el[(S) * HEADS + head] + ern;                     \
        x = (x > 0.f) ? x : 0.2f * x;                               \
        float ex = __expf(x);                                       \
        den += ex;                                                  \
        ushort4 fv = *(const ushort4*)(feat + (size_t)(S) * FF + f0);\
        a0 += b2f(fv.x) * ex;                                       \
        a1 += b2f(fv.y) * ex;                                       \
        a2 += b2f(fv.z) * ex;                                       \
        a3 += b2f(fv.w) * ex; }

    int j = j0;
    for (; j + 4 <= j1; j += 4) {
        int s0 = src_perm[j + 0];
        int s1 = src_perm[j + 1];
        int s2 = src_perm[j + 2];
        int s3 = src_perm[j + 3];
        EDGE_STEP(s0); EDGE_STEP(s1); EDGE_STEP(s2); EDGE_STEP(s3);
    }
    for (; j < j1; ++j) {
        int s = src_perm[j];
        EDGE_STEP(s);
    }
#undef EDGE_STEP

    if (den <= 0.f) den = 1.f;
    float inv = 1.f / den;
    float4 bv = *(const float4*)(bias + f0);
    float o0 = a0 * inv + bv.x;
    float o1 = a1 * inv + bv.y;
    float o2 = a2 * inv + bv.z;
    float o3 = a3 * inv + bv.w;
    float4 r;
    r.x = (o0 > 0.f) ? o0 : (__expf(o0) - 1.f);
    r.y = (o1 > 0.f) ? o1 : (__expf(o1) - 1.f);
    r.z = (o2 > 0.f) ? o2 : (__expf(o2) - 1.f);
    r.w = (o3 > 0.f) ? o3 : (__expf(o3) - 1.f);
    *(float4*)(z + (size_t)n * FF + f0) = r;
}

// qsum[idx] += sum_n tanh(z[n]@Wsem + bsem) @ wsem   (32 nodes per block)
__global__ __launch_bounds__(256) void sem_kernel(
    const float* __restrict__ z,      // [N,256] fp32
    const float* __restrict__ Wsem,   // [256,128]
    const float* __restrict__ bsem,   // [128]
    const float* __restrict__ wsem,   // [128]
    float* __restrict__ qsum, int idx)
{
    __shared__ float zs[32][FF];   // 32KB; reused as reduction buffer later
    __shared__ float qn[32];
    const int t = threadIdx.x;
    const int n0 = blockIdx.x * 32;
    #pragma unroll
    for (int it = 0; it < 8; ++it) {
        int v = t + it * 256;      // 2048 x float4 total
        int row = v >> 6;          // 64 float4 per row
        int c4 = (v & 63) * 4;
        int n = n0 + row;
        float4 d = make_float4(0.f, 0.f, 0.f, 0.f);
        if (n < NN) d = *(const float4*)(z + (size_t)n * FF + c4);
        *(float4*)&zs[row][c4] = d;
    }
    __syncthreads();
    const int j = t & 127;
    const int half = t >> 7;
    float val[16];
    #pragma unroll
    for (int i = 0; i < 16; ++i) val[i] = 0.f;
    for (int f = 0; f < FF; f += 4) {
        float w0 = Wsem[(size_t)(f + 0) * SH + j];
        float w1 = Wsem[(size_t)(f + 1) * SH + j];
        float w2 = Wsem[(size_t)(f + 2) * SH + j];
        float w3 = Wsem[(size_t)(f + 3) * SH + j];
        #pragma unroll
        for (int i = 0; i < 16; ++i) {
            float4 zv = *(const float4*)&zs[half * 16 + i][f];
            val[i] += zv.x * w0 + zv.y * w1 + zv.z * w2 + zv.w * w3;
        }
    }
    float bj = bsem[j];
    float wj = wsem[j];
    __syncthreads();
    float* red = &zs[0][0];        // [32][128]
    #pragma unroll
    for (int i = 0; i < 16; ++i)
        red[(half * 16 + i) * SH + j] = tanhf(val[i] + bj) * wj;
    __syncthreads();
    int node = t >> 3, k = t & 7;
    float s = 0.f;
    #pragma unroll
    for (int u = 0; u < 16; ++u) s += red[node * SH + k * 16 + u];
    #pragma unroll
    for (int o = 4; o > 0; o >>= 1) s += __shfl_down(s, o, 8);
    if (k == 0) qn[node] = s;
    __syncthreads();
    if (t == 0) {
        int nv = NN - n0; if (nv > 32) nv = 32;
        float tot = 0.f;
        for (int i = 0; i < nv; ++i) tot += qn[i];
        atomicAdd(&qsum[idx], tot);
    }
}

// out = beta0*z_a + beta1*z_b   (z_b already in out; beta from qsum inline)
__global__ void combine_kernel(const float* __restrict__ za,
                               float* __restrict__ out,
                               const float* __restrict__ qsum)
{
    size_t i = (size_t)blockIdx.x * blockDim.x + threadIdx.x;
    size_t base = i * 4;
    if (base >= (size_t)NN * FF) return;
    float qa = qsum[0] * (1.f / NN), qb = qsum[1] * (1.f / NN);
    float mx = fmaxf(qa, qb);
    float ea = __expf(qa - mx), eb = __expf(qb - mx);
    float inv = 1.f / (ea + eb);
    float b0 = ea * inv, b1 = eb * inv;
    float4 va = *(const float4*)(za + base);
    float4 vb = *(const float4*)(out + base);
    float4 r;
    r.x = b0 * va.x + b1 * vb.x;
    r.y = b0 * va.y + b1 * vb.y;
    r.z = b0 * va.z + b1 * vb.z;
    r.w = b0 * va.w + b1 * vb.w;
    *(float4*)(out + base) = r;
}

extern "C" void kernel_launch(void* const* d_in, const int* in_sizes, int n_in,
                              void* d_out, int out_size, void* d_ws, size_t ws_size,
                              hipStream_t stream)
{
    const float* h      = (const float*)d_in[0];
    const int* src_a    = (const int*)d_in[1];
    const int* dst_a    = (const int*)d_in[2];
    const int* src_b    = (const int*)d_in[3];
    const int* dst_b    = (const int*)d_in[4];
    const float* W_a    = (const float*)d_in[5];
    const float* al_a   = (const float*)d_in[6];
    const float* ar_a   = (const float*)d_in[7];
    const float* bias_a = (const float*)d_in[8];
    const float* W_b    = (const float*)d_in[9];
    const float* al_b   = (const float*)d_in[10];
    const float* ar_b   = (const float*)d_in[11];
    const float* bias_b = (const float*)d_in[12];
    const float* Wsem   = (const float*)d_in[13];
    const float* bsem   = (const float*)d_in[14];
    const float* wsem   = (const float*)d_in[15];
    float* out = (float*)d_out;

    char* ws = (char*)d_ws;
    size_t o = 0;
    auto alloc = [&](size_t bytes) -> char* {
        char* p = ws + o;
        o += (bytes + 255) & ~(size_t)255;
        return p;
    };
    unsigned short* feat = (unsigned short*)alloc((size_t)NN * FF * 2); // bf16
    float* z_a     = (float*)alloc((size_t)NN * FF * 4);
    float* el      = (float*)alloc((size_t)NN * HEADS * 4);
    float* er      = (float*)alloc((size_t)NN * HEADS * 4);
    int* counts    = (int*)alloc((size_t)NN * 4);
    int* offs      = (int*)alloc((size_t)(NN + 1) * 4);
    int* cursor    = (int*)alloc((size_t)NN * 4);
    int* bsums     = (int*)alloc(256 * 4);
    int* src_perm  = (int*)alloc((size_t)EE * 4);
    float* qsum    = (float*)alloc(8);

    hipMemsetAsync(qsum, 0, 8, stream);

    const int nblk_scan = (NN + 255) / 256;

    for (int mp = 0; mp < 2; ++mp) {
        const int* src = mp ? src_b : src_a;
        const int* dst = mp ? dst_b : dst_a;
        const float* W    = mp ? W_b : W_a;
        const float* al   = mp ? al_b : al_a;
        const float* ar   = mp ? ar_b : ar_a;
        const float* bias = mp ? bias_b : bias_a;
        float* z = mp ? out : z_a;

        gemm_feat_kernel<<<(NN + 31) / 32, 256, 0, stream>>>(h, W, feat);
        elr_kernel<<<NN, 256, 0, stream>>>(feat, al, ar, el, er);
        hipMemsetAsync(counts, 0, (size_t)NN * 4, stream);
        count_kernel<<<(EE + 255) / 256, 256, 0, stream>>>(dst, counts);
        scan1_kernel<<<nblk_scan, 256, 0, stream>>>(counts, offs, bsums);
        scan2_kernel<<<1, 256, 0, stream>>>(bsums, offs, nblk_scan);
        scan3_kernel<<<nblk_scan, 256, 0, stream>>>(offs, bsums, cursor);
        fill_kernel<<<(EE + 255) / 256, 256, 0, stream>>>(src, dst, cursor, src_perm);
        pull_kernel<<<(NN + 3) / 4, 256, 0, stream>>>(offs, src_perm, el, er, feat, bias, z);
        sem_kernel<<<(NN + 31) / 32, 256, 0, stream>>>(z, Wsem, bsem, wsem, qsum, mp);
    }
    combine_kernel<<<(int)(((size_t)NN * FF / 4 + 255) / 256), 256, 0, stream>>>(z_a, out, qsum);
}

// Round 5
// 709.965 us; speedup vs baseline: 1.2962x; 1.1430x over previous
//
#include <hip/hip_runtime.h>
#include <stdint.h>

#define NN 50000
#define EE 800000
#define IN_DIM 128
#define OUT_DIM 32
#define HEADS 8
#define FF 256
#define SH 128
#define NPAD 50048   // NN rounded up to 64

typedef short s16x8 __attribute__((ext_vector_type(8)));
typedef float f32x4 __attribute__((ext_vector_type(4)));

__device__ __forceinline__ float b2f(unsigned short u) {
    union { unsigned int i; float f; } v; v.i = ((unsigned int)u) << 16; return v.f;
}
__device__ __forceinline__ unsigned short f2b(float f) {
    union { float f; unsigned int i; } v; v.f = f;
    unsigned int i = v.i;
    unsigned int r = (i + 0x7FFFu + ((i >> 16) & 1u)) >> 16;
    return (unsigned short)r;
}

// feat[n, f] = sum_k h[n,k] * W[k,f]  (fp32 in, fp32 acc, bf16 out)
// + fused el/er: el[n,h] = sum_d feat[n,h,d]*al[h,d] (from fp32 acc)
__global__ __launch_bounds__(256) void gemm_feat_kernel(
    const float* __restrict__ h,   // [N,128]
    const float* __restrict__ W,   // [128,256]
    const float* __restrict__ al,  // [8,32] flat 256
    const float* __restrict__ ar,
    unsigned short* __restrict__ feat,   // [N,256] bf16
    float* __restrict__ el, float* __restrict__ er)  // [N,8]
{
    __shared__ float hs[32][IN_DIM];  // 16KB
    const int t = threadIdx.x;
    const int n0 = blockIdx.x * 32;
    #pragma unroll
    for (int it = 0; it < 4; ++it) {
        int v = t + it * 256;          // 1024 x float4 total
        int row = v >> 5;              // 32 float4 per row
        int c4 = (v & 31) * 4;
        int n = n0 + row;
        float4 d = make_float4(0.f, 0.f, 0.f, 0.f);
        if (n < NN) d = *(const float4*)(h + (size_t)n * IN_DIM + c4);
        *(float4*)&hs[row][c4] = d;
    }
    __syncthreads();
    float acc[32];
    #pragma unroll
    for (int i = 0; i < 32; ++i) acc[i] = 0.f;
    for (int kb = 0; kb < IN_DIM; kb += 8) {
        float wv[8];
        #pragma unroll
        for (int u = 0; u < 8; ++u) wv[u] = W[(size_t)(kb + u) * FF + t];
        #pragma unroll
        for (int i = 0; i < 32; ++i) {
            float4 h0 = *(const float4*)&hs[i][kb];
            float4 h1 = *(const float4*)&hs[i][kb + 4];
            acc[i] += h0.x * wv[0] + h0.y * wv[1] + h0.z * wv[2] + h0.w * wv[3]
                    + h1.x * wv[4] + h1.y * wv[5] + h1.z * wv[6] + h1.w * wv[7];
        }
    }
    #pragma unroll
    for (int i = 0; i < 32; ++i) {
        int n = n0 + i;
        if (n < NN) feat[(size_t)n * FF + t] = f2b(acc[i]);
    }
    // fused el/er: head = t>>5, d = t&31; reduce over the 32 lanes of each head
    float alv = al[t], arv = ar[t];
    int head = t >> 5;
    #pragma unroll
    for (int i = 0; i < 32; ++i) {
        float pl = acc[i] * alv;
        float pr = acc[i] * arv;
        #pragma unroll
        for (int o = 16; o > 0; o >>= 1) {
            pl += __shfl_xor(pl, o, 32);
            pr += __shfl_xor(pr, o, 32);
        }
        if ((t & 31) == 0) {
            int n = n0 + i;
            if (n < NN) {
                el[n * HEADS + head] = pl;
                er[n * HEADS + head] = pr;
            }
        }
    }
}

__global__ void count_kernel(const int* __restrict__ dst, int* __restrict__ counts) {
    int e = blockIdx.x * blockDim.x + threadIdx.x;
    if (e < EE) atomicAdd(&counts[dst[e]], 1);
}

__global__ __launch_bounds__(256) void scan1_kernel(
    const int* __restrict__ counts, int* __restrict__ offs, int* __restrict__ bsums)
{
    __shared__ int sm[256];
    int t = threadIdx.x, i = blockIdx.x * 256 + t;
    int v = (i < NN) ? counts[i] : 0;
    sm[t] = v; __syncthreads();
    for (int d = 1; d < 256; d <<= 1) {
        int x = (t >= d) ? sm[t - d] : 0;
        __syncthreads();
        sm[t] += x;
        __syncthreads();
    }
    if (i < NN) offs[i] = sm[t] - v;          // local exclusive
    if (t == 255) bsums[blockIdx.x] = sm[255]; // block total
}

__global__ __launch_bounds__(256) void scan2_kernel(
    int* __restrict__ bsums, int* __restrict__ offs, int nblk)
{
    __shared__ int sm[256];
    int t = threadIdx.x;
    int v = (t < nblk) ? bsums[t] : 0;
    sm[t] = v; __syncthreads();
    for (int d = 1; d < 256; d <<= 1) {
        int x = (t >= d) ? sm[t - d] : 0;
        __syncthreads();
        sm[t] += x;
        __syncthreads();
    }
    if (t < nblk) bsums[t] = sm[t] - v;
    if (t == 0) offs[NN] = EE;
}

__global__ __launch_bounds__(256) void scan3_kernel(
    int* __restrict__ offs, const int* __restrict__ bsums, int* __restrict__ cursor)
{
    int t = threadIdx.x, i = blockIdx.x * 256 + t;
    if (i < NN) {
        int v = offs[i] + bsums[blockIdx.x];
        offs[i] = v;
        cursor[i] = v;
    }
}

// scatter src index into CSR slots (4 B per edge)
__global__ void fill_kernel(const int* __restrict__ src, const int* __restrict__ dst,
                            int* __restrict__ cursor, int* __restrict__ src_perm)
{
    int e = blockIdx.x * blockDim.x + threadIdx.x;
    if (e >= EE) return;
    int slot = atomicAdd(&cursor[dst[e]], 1);
    src_perm[slot] = src[e];
}

// one wave per dst node, single pass: softmax (no max-shift; logits are small)
// + weighted feat aggregation + bias + ELU; writes z fp32 and z bf16
__global__ __launch_bounds__(256) void pull_kernel(
    const int* __restrict__ offs, const int* __restrict__ src_perm,
    const float* __restrict__ el, const float* __restrict__ er,
    const unsigned short* __restrict__ feat,
    const float* __restrict__ bias, float* __restrict__ z,
    unsigned short* __restrict__ zb)
{
    int wave = threadIdx.x >> 6;
    int lane = threadIdx.x & 63;
    int n = blockIdx.x * 4 + wave;
    if (n >= NN) return;
    int head = lane >> 3;     // 8 lanes per head
    int f0 = lane * 4;        // 4 contiguous features per lane, all same head
    int j0 = offs[n], j1 = offs[n + 1];
    float ern = er[n * HEADS + head];
    float den = 0.f;
    float a0 = 0.f, a1 = 0.f, a2 = 0.f, a3 = 0.f;

#define EDGE_STEP(S) {                                              \
        float x = el[(S) * HEADS + head] + ern;                     \
        x = (x > 0.f) ? x : 0.2f * x;                               \
        float ex = __expf(x);                                       \
        den += ex;                                                  \
        ushort4 fv = *(const ushort4*)(feat + (size_t)(S) * FF + f0);\
        a0 += b2f(fv.x) * ex;                                       \
        a1 += b2f(fv.y) * ex;                                       \
        a2 += b2f(fv.z) * ex;                                       \
        a3 += b2f(fv.w) * ex; }

    int j = j0;
    for (; j + 4 <= j1; j += 4) {
        int s0 = src_perm[j + 0];
        int s1 = src_perm[j + 1];
        int s2 = src_perm[j + 2];
        int s3 = src_perm[j + 3];
        EDGE_STEP(s0); EDGE_STEP(s1); EDGE_STEP(s2); EDGE_STEP(s3);
    }
    for (; j < j1; ++j) {
        int s = src_perm[j];
        EDGE_STEP(s);
    }
#undef EDGE_STEP

    if (den <= 0.f) den = 1.f;
    float inv = 1.f / den;
    float4 bv = *(const float4*)(bias + f0);
    float o0 = a0 * inv + bv.x;
    float o1 = a1 * inv + bv.y;
    float o2 = a2 * inv + bv.z;
    float o3 = a3 * inv + bv.w;
    float4 r;
    r.x = (o0 > 0.f) ? o0 : (__expf(o0) - 1.f);
    r.y = (o1 > 0.f) ? o1 : (__expf(o1) - 1.f);
    r.z = (o2 > 0.f) ? o2 : (__expf(o2) - 1.f);
    r.w = (o3 > 0.f) ? o3 : (__expf(o3) - 1.f);
    *(float4*)(z + (size_t)n * FF + f0) = r;
    ushort4 rb;
    rb.x = f2b(r.x); rb.y = f2b(r.y); rb.z = f2b(r.z); rb.w = f2b(r.w);
    *(ushort4*)(zb + (size_t)n * FF + f0) = rb;
}

// WsemT[j, k] = bf16(Wsem[k, j])
__global__ void wsemT_kernel(const float* __restrict__ Wsem,
                             unsigned short* __restrict__ WsemT)
{
    int j = blockIdx.x, k = threadIdx.x;
    WsemT[j * FF + k] = f2b(Wsem[(size_t)k * SH + j]);
}

// qsum[idx] += sum_n tanh(z[n]@Wsem + bsem) @ wsem via bf16 MFMA.
// 64 nodes/block, wave w: nodes [16w,16w+16), all 128 j.
__global__ __launch_bounds__(256) void sem_mfma_kernel(
    const unsigned short* __restrict__ zb,     // [NPAD,256] bf16
    const unsigned short* __restrict__ WsemT,  // [128,256] bf16 (j-major)
    const float* __restrict__ bsem, const float* __restrict__ wsem,
    float* __restrict__ qsum, int idx)
{
    int wave = threadIdx.x >> 6, lane = threadIdx.x & 63;
    int quad = lane >> 4, l16 = lane & 15;
    int nbase = blockIdx.x * 64 + wave * 16;
    // A-frags: A[m=l16][k=quad*8+u], all 8 K-tiles resident (32 VGPR)
    const unsigned short* arow = zb + (size_t)(nbase + l16) * FF + quad * 8;
    s16x8 afr[8];
    #pragma unroll
    for (int kt = 0; kt < 8; ++kt)
        afr[kt] = *(const s16x8*)(arow + kt * 32);
    float qacc = 0.f;
    for (int jt = 0; jt < 8; ++jt) {
        int jj = jt * 16 + l16;
        const unsigned short* brow = WsemT + (size_t)jj * FF + quad * 8;
        f32x4 c = {0.f, 0.f, 0.f, 0.f};
        #pragma unroll
        for (int kt = 0; kt < 8; ++kt) {
            s16x8 bfr = *(const s16x8*)(brow + kt * 32);
            c = __builtin_amdgcn_mfma_f32_16x16x32_bf16(afr[kt], bfr, c, 0, 0, 0);
        }
        float bj = bsem[jj], wj = wsem[jj];
        #pragma unroll
        for (int r = 0; r < 4; ++r) {
            int n = nbase + quad * 4 + r;   // C row = quad*4+reg, col = l16
            float tv = tanhf(c[r] + bj) * wj;
            qacc += (n < NN) ? tv : 0.f;
        }
    }
    #pragma unroll
    for (int o = 1; o < 64; o <<= 1) qacc += __shfl_xor(qacc, o, 64);
    __shared__ float wsum[4];
    if (lane == 0) wsum[wave] = qacc;
    __syncthreads();
    if (threadIdx.x == 0)
        atomicAdd(&qsum[idx], wsum[0] + wsum[1] + wsum[2] + wsum[3]);
}

// out = beta0*z_a + beta1*z_b   (z_b already in out; beta from qsum inline)
__global__ void combine_kernel(const float* __restrict__ za,
                               float* __restrict__ out,
                               const float* __restrict__ qsum)
{
    size_t i = (size_t)blockIdx.x * blockDim.x + threadIdx.x;
    size_t base = i * 4;
    if (base >= (size_t)NN * FF) return;
    float qa = qsum[0] * (1.f / NN), qb = qsum[1] * (1.f / NN);
    float mx = fmaxf(qa, qb);
    float ea = __expf(qa - mx), eb = __expf(qb - mx);
    float inv = 1.f / (ea + eb);
    float b0 = ea * inv, b1 = eb * inv;
    float4 va = *(const float4*)(za + base);
    float4 vb = *(const float4*)(out + base);
    float4 r;
    r.x = b0 * va.x + b1 * vb.x;
    r.y = b0 * va.y + b1 * vb.y;
    r.z = b0 * va.z + b1 * vb.z;
    r.w = b0 * va.w + b1 * vb.w;
    *(float4*)(out + base) = r;
}

extern "C" void kernel_launch(void* const* d_in, const int* in_sizes, int n_in,
                              void* d_out, int out_size, void* d_ws, size_t ws_size,
                              hipStream_t stream)
{
    const float* h      = (const float*)d_in[0];
    const int* src_a    = (const int*)d_in[1];
    const int* dst_a    = (const int*)d_in[2];
    const int* src_b    = (const int*)d_in[3];
    const int* dst_b    = (const int*)d_in[4];
    const float* W_a    = (const float*)d_in[5];
    const float* al_a   = (const float*)d_in[6];
    const float* ar_a   = (const float*)d_in[7];
    const float* bias_a = (const float*)d_in[8];
    const float* W_b    = (const float*)d_in[9];
    const float* al_b   = (const float*)d_in[10];
    const float* ar_b   = (const float*)d_in[11];
    const float* bias_b = (const float*)d_in[12];
    const float* Wsem   = (const float*)d_in[13];
    const float* bsem   = (const float*)d_in[14];
    const float* wsem   = (const float*)d_in[15];
    float* out = (float*)d_out;

    char* ws = (char*)d_ws;
    size_t o = 0;
    auto alloc = [&](size_t bytes) -> char* {
        char* p = ws + o;
        o += (bytes + 255) & ~(size_t)255;
        return p;
    };
    unsigned short* feat  = (unsigned short*)alloc((size_t)NN * FF * 2);   // bf16
    float* z_a            = (float*)alloc((size_t)NN * FF * 4);
    unsigned short* zb    = (unsigned short*)alloc((size_t)NPAD * FF * 2); // bf16
    unsigned short* WsemT = (unsigned short*)alloc((size_t)SH * FF * 2);   // bf16
    float* el      = (float*)alloc((size_t)NN * HEADS * 4);
    float* er      = (float*)alloc((size_t)NN * HEADS * 4);
    int* counts    = (int*)alloc((size_t)NN * 4);
    int* offs      = (int*)alloc((size_t)(NN + 1) * 4);
    int* cursor    = (int*)alloc((size_t)NN * 4);
    int* bsums     = (int*)alloc(256 * 4);
    int* src_perm  = (int*)alloc((size_t)EE * 4);
    float* qsum    = (float*)alloc(8);

    hipMemsetAsync(qsum, 0, 8, stream);
    wsemT_kernel<<<SH, FF, 0, stream>>>(Wsem, WsemT);

    const int nblk_scan = (NN + 255) / 256;

    for (int mp = 0; mp < 2; ++mp) {
        const int* src = mp ? src_b : src_a;
        const int* dst = mp ? dst_b : dst_a;
        const float* W    = mp ? W_b : W_a;
        const float* al   = mp ? al_b : al_a;
        const float* ar   = mp ? ar_b : ar_a;
        const float* bias = mp ? bias_b : bias_a;
        float* z = mp ? out : z_a;

        gemm_feat_kernel<<<(NN + 31) / 32, 256, 0, stream>>>(h, W, al, ar, feat, el, er);
        hipMemsetAsync(counts, 0, (size_t)NN * 4, stream);
        count_kernel<<<(EE + 255) / 256, 256, 0, stream>>>(dst, counts);
        scan1_kernel<<<nblk_scan, 256, 0, stream>>>(counts, offs, bsums);
        scan2_kernel<<<1, 256, 0, stream>>>(bsums, offs, nblk_scan);
        scan3_kernel<<<nblk_scan, 256, 0, stream>>>(offs, bsums, cursor);
        fill_kernel<<<(EE + 255) / 256, 256, 0, stream>>>(src, dst, cursor, src_perm);
        pull_kernel<<<(NN + 3) / 4, 256, 0, stream>>>(offs, src_perm, el, er, feat, bias, z, zb);
        sem_mfma_kernel<<<(NN + 63) / 64, 256, 0, stream>>>(zb, WsemT, bsem, wsem, qsum, mp);
    }
    combine_kernel<<<(int)(((size_t)NN * FF / 4 + 255) / 256), 256, 0, stream>>>(z_a, out, qsum);
}

// Round 6
// 584.710 us; speedup vs baseline: 1.5738x; 1.2142x over previous
//
#include <hip/hip_runtime.h>
#include <stdint.h>

#define NN 50000
#define EE 800000
#define IN_DIM 128
#define OUT_DIM 32
#define HEADS 8
#define FF 256
#define SH 128
#define NPAD 50048   // NN rounded up to 64
#define FEXT 272     // 256 feat cols + 8 el-proj + 8 er-proj

typedef short s16x8 __attribute__((ext_vector_type(8)));
typedef float f32x4 __attribute__((ext_vector_type(4)));

__device__ __forceinline__ float b2f(unsigned short u) {
    union { unsigned int i; float f; } v; v.i = ((unsigned int)u) << 16; return v.f;
}
__device__ __forceinline__ unsigned short f2b(float f) {
    union { float f; unsigned int i; } v; v.f = f;
    unsigned int i = v.i;
    unsigned int r = (i + 0x7FFFu + ((i >> 16) & 1u)) >> 16;
    return (unsigned short)r;
}

// h [NN,128] fp32 -> hb [NPAD,128] bf16 (pad rows zeroed)
__global__ __launch_bounds__(256) void h2b_kernel(const float* __restrict__ h,
                                                  unsigned short* __restrict__ hb)
{
    int i = (blockIdx.x * 256 + threadIdx.x) * 4;
    if (i >= NPAD * IN_DIM) return;
    int row = i >> 7;
    ushort4 r;
    if (row < NN) {
        float4 v = *(const float4*)(h + i);
        r.x = f2b(v.x); r.y = f2b(v.y); r.z = f2b(v.z); r.w = f2b(v.w);
    } else {
        r.x = r.y = r.z = r.w = 0;
    }
    *(ushort4*)(hb + i) = r;
}

// BT[f', k] bf16: f'<256 -> W[k,f']; f'=256+j (j<8) -> sum_d W[k,j*32+d]*al[j*32+d];
// f'=264+j -> same with ar.
__global__ __launch_bounds__(128) void buildBT_kernel(
    const float* __restrict__ W, const float* __restrict__ al,
    const float* __restrict__ ar, unsigned short* __restrict__ BT)
{
    int fp = blockIdx.x, k = threadIdx.x;
    float v;
    if (fp < FF) {
        v = W[(size_t)k * FF + fp];
    } else if (fp < FF + 8) {
        int hh = fp - FF;
        float s = 0.f;
        #pragma unroll
        for (int d = 0; d < 32; ++d) s += W[(size_t)k * FF + hh * 32 + d] * al[hh * 32 + d];
        v = s;
    } else {
        int hh = fp - FF - 8;
        float s = 0.f;
        #pragma unroll
        for (int d = 0; d < 32; ++d) s += W[(size_t)k * FF + hh * 32 + d] * ar[hh * 32 + d];
        v = s;
    }
    BT[(size_t)fp * IN_DIM + k] = f2b(v);
}

// MFMA GEMM: feat[n,f]=h@W (bf16), el/er fused as extra output columns.
// Block = 4 waves x 16 nodes; wave covers 17 f-tiles of 16.
// mfma(A=BT f-row, B=hb node-row): C[row=quad*4+r -> f, col=l16 -> node].
__global__ __launch_bounds__(256) void gemm_feat_mfma(
    const unsigned short* __restrict__ hb,   // [NPAD,128] bf16
    const unsigned short* __restrict__ BT,   // [272,128] bf16
    unsigned short* __restrict__ feat,       // [NN,256] bf16
    float* __restrict__ el, float* __restrict__ er)  // [NN,8]
{
    int wave = threadIdx.x >> 6, lane = threadIdx.x & 63;
    int quad = lane >> 4, l16 = lane & 15;
    int nbase = blockIdx.x * 64 + wave * 16;
    int n = nbase + l16;
    const unsigned short* arow = hb + (size_t)n * IN_DIM + quad * 8;
    s16x8 nfr[4];
    #pragma unroll
    for (int kt = 0; kt < 4; ++kt)
        nfr[kt] = *(const s16x8*)(arow + kt * 32);
    bool live = (n < NN);
    #pragma unroll 1
    for (int ft = 0; ft < 17; ++ft) {
        const unsigned short* brow = BT + (size_t)(ft * 16 + l16) * IN_DIM + quad * 8;
        f32x4 c = {0.f, 0.f, 0.f, 0.f};
        #pragma unroll
        for (int kt = 0; kt < 4; ++kt) {
            s16x8 ffr = *(const s16x8*)(brow + kt * 32);
            c = __builtin_amdgcn_mfma_f32_16x16x32_bf16(ffr, nfr[kt], c, 0, 0, 0);
        }
        if (ft < 16) {
            if (live) {
                ushort4 r;
                r.x = f2b(c[0]); r.y = f2b(c[1]); r.z = f2b(c[2]); r.w = f2b(c[3]);
                *(ushort4*)(feat + (size_t)n * FF + ft * 16 + quad * 4) = r;
            }
        } else {
            if (live) {
                #pragma unroll
                for (int r = 0; r < 4; ++r) {
                    int jp = quad * 4 + r;
                    if (jp < 8) el[n * HEADS + jp] = c[r];
                    else        er[n * HEADS + (jp - 8)] = c[r];
                }
            }
        }
    }
}

__global__ void count_kernel(const int* __restrict__ dst, int* __restrict__ counts) {
    int e = blockIdx.x * blockDim.x + threadIdx.x;
    if (e < EE) atomicAdd(&counts[dst[e]], 1);
}

__global__ __launch_bounds__(256) void scan1_kernel(
    const int* __restrict__ counts, int* __restrict__ offs, int* __restrict__ bsums)
{
    __shared__ int sm[256];
    int t = threadIdx.x, i = blockIdx.x * 256 + t;
    int v = (i < NN) ? counts[i] : 0;
    sm[t] = v; __syncthreads();
    for (int d = 1; d < 256; d <<= 1) {
        int x = (t >= d) ? sm[t - d] : 0;
        __syncthreads();
        sm[t] += x;
        __syncthreads();
    }
    if (i < NN) offs[i] = sm[t] - v;          // local exclusive
    if (t == 255) bsums[blockIdx.x] = sm[255]; // block total
}

__global__ __launch_bounds__(256) void scan2_kernel(
    int* __restrict__ bsums, int* __restrict__ offs, int nblk)
{
    __shared__ int sm[256];
    int t = threadIdx.x;
    int v = (t < nblk) ? bsums[t] : 0;
    sm[t] = v; __syncthreads();
    for (int d = 1; d < 256; d <<= 1) {
        int x = (t >= d) ? sm[t - d] : 0;
        __syncthreads();
        sm[t] += x;
        __syncthreads();
    }
    if (t < nblk) bsums[t] = sm[t] - v;
    if (t == 0) offs[NN] = EE;
}

__global__ __launch_bounds__(256) void scan3_kernel(
    int* __restrict__ offs, const int* __restrict__ bsums, int* __restrict__ cursor)
{
    int t = threadIdx.x, i = blockIdx.x * 256 + t;
    if (i < NN) {
        int v = offs[i] + bsums[blockIdx.x];
        offs[i] = v;
        cursor[i] = v;
    }
}

// scatter src index into CSR slots (4 B per edge)
__global__ void fill_kernel(const int* __restrict__ src, const int* __restrict__ dst,
                            int* __restrict__ cursor, int* __restrict__ src_perm)
{
    int e = blockIdx.x * blockDim.x + threadIdx.x;
    if (e >= EE) return;
    int slot = atomicAdd(&cursor[dst[e]], 1);
    src_perm[slot] = src[e];
}

// one wave per dst node, single pass: softmax (no max-shift; logits are small)
// + weighted feat aggregation + bias + ELU; writes z bf16
__global__ __launch_bounds__(256) void pull_kernel(
    const int* __restrict__ offs, const int* __restrict__ src_perm,
    const float* __restrict__ el, const float* __restrict__ er,
    const unsigned short* __restrict__ feat,
    const float* __restrict__ bias, unsigned short* __restrict__ zb)
{
    int wave = threadIdx.x >> 6;
    int lane = threadIdx.x & 63;
    int n = blockIdx.x * 4 + wave;
    if (n >= NN) return;
    int head = lane >> 3;     // 8 lanes per head
    int f0 = lane * 4;        // 4 contiguous features per lane, all same head
    int j0 = offs[n], j1 = offs[n + 1];
    float ern = er[n * HEADS + head];
    float den = 0.f;
    float a0 = 0.f, a1 = 0.f, a2 = 0.f, a3 = 0.f;

#define EDGE_STEP(S) {                                              \
        float x = el[(S) * HEADS + head] + ern;                     \
        x = (x > 0.f) ? x : 0.2f * x;                               \
        float ex = __expf(x);                                       \
        den += ex;                                                  \
        ushort4 fv = *(const ushort4*)(feat + (size_t)(S) * FF + f0);\
        a0 += b2f(fv.x) * ex;                                       \
        a1 += b2f(fv.y) * ex;                                       \
        a2 += b2f(fv.z) * ex;                                       \
        a3 += b2f(fv.w) * ex; }

    int j = j0;
    for (; j + 4 <= j1; j += 4) {
        int s0 = src_perm[j + 0];
        int s1 = src_perm[j + 1];
        int s2 = src_perm[j + 2];
        int s3 = src_perm[j + 3];
        EDGE_STEP(s0); EDGE_STEP(s1); EDGE_STEP(s2); EDGE_STEP(s3);
    }
    for (; j < j1; ++j) {
        int s = src_perm[j];
        EDGE_STEP(s);
    }
#undef EDGE_STEP

    if (den <= 0.f) den = 1.f;
    float inv = 1.f / den;
    float4 bv = *(const float4*)(bias + f0);
    float o0 = a0 * inv + bv.x;
    float o1 = a1 * inv + bv.y;
    float o2 = a2 * inv + bv.z;
    float o3 = a3 * inv + bv.w;
    ushort4 rb;
    rb.x = f2b((o0 > 0.f) ? o0 : (__expf(o0) - 1.f));
    rb.y = f2b((o1 > 0.f) ? o1 : (__expf(o1) - 1.f));
    rb.z = f2b((o2 > 0.f) ? o2 : (__expf(o2) - 1.f));
    rb.w = f2b((o3 > 0.f) ? o3 : (__expf(o3) - 1.f));
    *(ushort4*)(zb + (size_t)n * FF + f0) = rb;
}

// WsemT[j, k] = bf16(Wsem[k, j])
__global__ void wsemT_kernel(const float* __restrict__ Wsem,
                             unsigned short* __restrict__ WsemT)
{
    int j = blockIdx.x, k = threadIdx.x;
    WsemT[j * FF + k] = f2b(Wsem[(size_t)k * SH + j]);
}

// qsum[idx] += sum_n tanh(z[n]@Wsem + bsem) @ wsem via bf16 MFMA.
// 64 nodes/block, wave w: nodes [16w,16w+16), all 128 j.
__global__ __launch_bounds__(256) void sem_mfma_kernel(
    const unsigned short* __restrict__ zb,     // [NPAD,256] bf16
    const unsigned short* __restrict__ WsemT,  // [128,256] bf16 (j-major)
    const float* __restrict__ bsem, const float* __restrict__ wsem,
    float* __restrict__ qsum, int idx)
{
    int wave = threadIdx.x >> 6, lane = threadIdx.x & 63;
    int quad = lane >> 4, l16 = lane & 15;
    int nbase = blockIdx.x * 64 + wave * 16;
    const unsigned short* arow = zb + (size_t)(nbase + l16) * FF + quad * 8;
    s16x8 afr[8];
    #pragma unroll
    for (int kt = 0; kt < 8; ++kt)
        afr[kt] = *(const s16x8*)(arow + kt * 32);
    float qacc = 0.f;
    for (int jt = 0; jt < 8; ++jt) {
        int jj = jt * 16 + l16;
        const unsigned short* brow = WsemT + (size_t)jj * FF + quad * 8;
        f32x4 c = {0.f, 0.f, 0.f, 0.f};
        #pragma unroll
        for (int kt = 0; kt < 8; ++kt) {
            s16x8 bfr = *(const s16x8*)(brow + kt * 32);
            c = __builtin_amdgcn_mfma_f32_16x16x32_bf16(afr[kt], bfr, c, 0, 0, 0);
        }
        float bj = bsem[jj], wj = wsem[jj];
        #pragma unroll
        for (int r = 0; r < 4; ++r) {
            int n = nbase + quad * 4 + r;   // C row = quad*4+reg, col = l16
            float tv = tanhf(c[r] + bj) * wj;
            qacc += (n < NN) ? tv : 0.f;
        }
    }
    #pragma unroll
    for (int o = 1; o < 64; o <<= 1) qacc += __shfl_xor(qacc, o, 64);
    __shared__ float wsum[4];
    if (lane == 0) wsum[wave] = qacc;
    __syncthreads();
    if (threadIdx.x == 0)
        atomicAdd(&qsum[idx], wsum[0] + wsum[1] + wsum[2] + wsum[3]);
}

// out = beta0*za + beta1*zbm  (bf16 in, fp32 out; beta from qsum inline)
__global__ void combine_kernel(const unsigned short* __restrict__ za,
                               const unsigned short* __restrict__ zbm,
                               float* __restrict__ out,
                               const float* __restrict__ qsum)
{
    size_t i = (size_t)blockIdx.x * blockDim.x + threadIdx.x;
    size_t base = i * 4;
    if (base >= (size_t)NN * FF) return;
    float qa = qsum[0] * (1.f / NN), qb = qsum[1] * (1.f / NN);
    float mx = fmaxf(qa, qb);
    float ea = __expf(qa - mx), eb = __expf(qb - mx);
    float inv = 1.f / (ea + eb);
    float b0 = ea * inv, b1 = eb * inv;
    ushort4 va = *(const ushort4*)(za + base);
    ushort4 vb = *(const ushort4*)(zbm + base);
    float4 r;
    r.x = b0 * b2f(va.x) + b1 * b2f(vb.x);
    r.y = b0 * b2f(va.y) + b1 * b2f(vb.y);
    r.z = b0 * b2f(va.z) + b1 * b2f(vb.z);
    r.w = b0 * b2f(va.w) + b1 * b2f(vb.w);
    *(float4*)(out + base) = r;
}

extern "C" void kernel_launch(void* const* d_in, const int* in_sizes, int n_in,
                              void* d_out, int out_size, void* d_ws, size_t ws_size,
                              hipStream_t stream)
{
    const float* h      = (const float*)d_in[0];
    const int* src_a    = (const int*)d_in[1];
    const int* dst_a    = (const int*)d_in[2];
    const int* src_b    = (const int*)d_in[3];
    const int* dst_b    = (const int*)d_in[4];
    const float* W_a    = (const float*)d_in[5];
    const float* al_a   = (const float*)d_in[6];
    const float* ar_a   = (const float*)d_in[7];
    const float* bias_a = (const float*)d_in[8];
    const float* W_b    = (const float*)d_in[9];
    const float* al_b   = (const float*)d_in[10];
    const float* ar_b   = (const float*)d_in[11];
    const float* bias_b = (const float*)d_in[12];
    const float* Wsem   = (const float*)d_in[13];
    const float* bsem   = (const float*)d_in[14];
    const float* wsem   = (const float*)d_in[15];
    float* out = (float*)d_out;

    char* ws = (char*)d_ws;
    size_t o = 0;
    auto alloc = [&](size_t bytes) -> char* {
        char* p = ws + o;
        o += (bytes + 255) & ~(size_t)255;
        return p;
    };
    unsigned short* hb    = (unsigned short*)alloc((size_t)NPAD * IN_DIM * 2); // bf16
    unsigned short* BT    = (unsigned short*)alloc((size_t)FEXT * IN_DIM * 2); // bf16
    unsigned short* feat  = (unsigned short*)alloc((size_t)NN * FF * 2);       // bf16
    unsigned short* zb_a  = (unsigned short*)alloc((size_t)NPAD * FF * 2);     // bf16
    unsigned short* zb_b  = (unsigned short*)alloc((size_t)NPAD * FF * 2);     // bf16
    unsigned short* WsemT = (unsigned short*)alloc((size_t)SH * FF * 2);       // bf16
    float* el      = (float*)alloc((size_t)NN * HEADS * 4);
    float* er      = (float*)alloc((size_t)NN * HEADS * 4);
    int* counts    = (int*)alloc((size_t)NN * 4);
    int* offs      = (int*)alloc((size_t)(NN + 1) * 4);
    int* cursor    = (int*)alloc((size_t)NN * 4);
    int* bsums     = (int*)alloc(256 * 4);
    int* src_perm  = (int*)alloc((size_t)EE * 4);
    float* qsum    = (float*)alloc(8);

    hipMemsetAsync(qsum, 0, 8, stream);
    wsemT_kernel<<<SH, FF, 0, stream>>>(Wsem, WsemT);
    h2b_kernel<<<(NPAD * IN_DIM / 4 + 255) / 256, 256, 0, stream>>>(h, hb);

    const int nblk_scan = (NN + 255) / 256;

    for (int mp = 0; mp < 2; ++mp) {
        const int* src = mp ? src_b : src_a;
        const int* dst = mp ? dst_b : dst_a;
        const float* W    = mp ? W_b : W_a;
        const float* al   = mp ? al_b : al_a;
        const float* ar   = mp ? ar_b : ar_a;
        const float* bias = mp ? bias_b : bias_a;
        unsigned short* zb = mp ? zb_b : zb_a;

        buildBT_kernel<<<FEXT, 128, 0, stream>>>(W, al, ar, BT);
        gemm_feat_mfma<<<NPAD / 64, 256, 0, stream>>>(hb, BT, feat, el, er);
        hipMemsetAsync(counts, 0, (size_t)NN * 4, stream);
        count_kernel<<<(EE + 255) / 256, 256, 0, stream>>>(dst, counts);
        scan1_kernel<<<nblk_scan, 256, 0, stream>>>(counts, offs, bsums);
        scan2_kernel<<<1, 256, 0, stream>>>(bsums, offs, nblk_scan);
        scan3_kernel<<<nblk_scan, 256, 0, stream>>>(offs, bsums, cursor);
        fill_kernel<<<(EE + 255) / 256, 256, 0, stream>>>(src, dst, cursor, src_perm);
        pull_kernel<<<(NN + 3) / 4, 256, 0, stream>>>(offs, src_perm, el, er, feat, bias, zb);
        sem_mfma_kernel<<<(NN + 63) / 64, 256, 0, stream>>>(zb, WsemT, bsem, wsem, qsum, mp);
    }
    combine_kernel<<<(int)(((size_t)NN * FF / 4 + 255) / 256), 256, 0, stream>>>(zb_a, zb_b, out, qsum);
}